// Round 1
// baseline (329.848 us; speedup 1.0000x reference)
//
#include <hip/hip_runtime.h>
#include <math.h>

#define TEX_W 2048
#define TEX_H 2048

__device__ __forceinline__ float fast_tanh(float x) {
    // tanh(x) = 1 - 2/(exp(2x)+1); saturates correctly at +-inf
    float e = __expf(2.0f * x);
    return 1.0f - 2.0f * __builtin_amdgcn_rcpf(e + 1.0f);
}

__global__ void __launch_bounds__(256)
difftex_kernel(const float2* __restrict__ uvs,
               const float* __restrict__ tex,
               float* __restrict__ out, int n) {
    int i = blockIdx.x * blockDim.x + threadIdx.x;
    if (i >= n) return;

    float2 uv = uvs[i];
    float u = (uv.x + 1.0f) * 0.5f * (float)(TEX_W - 1);
    float v = (uv.y + 1.0f) * 0.5f * (float)(TEX_H - 1);

    float fu0 = floorf(u);
    float fv0 = floorf(v);
    int u0 = (int)fu0;
    int v0 = (int)fv0;
    int u1 = (int)ceilf(u);
    int v1 = (int)ceilf(v);
    float a = u - fu0;
    float b = v - fv0;
    float one_a = 1.0f - a;
    float one_b = 1.0f - b;

    // reference indexes texture[u, v] -> u is the row index
    const float* p00 = tex + ((long)u0 * TEX_W + v0) * 3;
    const float* p10 = tex + ((long)u1 * TEX_W + v0) * 3;
    const float* p01 = tex + ((long)u0 * TEX_W + v1) * 3;
    const float* p11 = tex + ((long)u1 * TEX_W + v1) * 3;

    float o0, o1, o2;
    {
        float c00 = p00[0], c10 = p10[0], c01 = p01[0], c11 = p11[0];
        float col = (c00 * a + c10 * one_a) * b + (c01 * a + c11 * one_a) * one_b;
        o0 = fast_tanh(col);
    }
    {
        float c00 = p00[1], c10 = p10[1], c01 = p01[1], c11 = p11[1];
        float col = (c00 * a + c10 * one_a) * b + (c01 * a + c11 * one_a) * one_b;
        o1 = fast_tanh(col);
    }
    {
        float c00 = p00[2], c10 = p10[2], c01 = p01[2], c11 = p11[2];
        float col = (c00 * a + c10 * one_a) * b + (c01 * a + c11 * one_a) * one_b;
        o2 = fast_tanh(col);
    }

    long base = (long)i * 3;
    out[base + 0] = o0;
    out[base + 1] = o1;
    out[base + 2] = o2;
}

extern "C" void kernel_launch(void* const* d_in, const int* in_sizes, int n_in,
                              void* d_out, int out_size, void* d_ws, size_t ws_size,
                              hipStream_t stream) {
    const float2* uvs = (const float2*)d_in[0];
    const float* tex = (const float*)d_in[1];
    float* out = (float*)d_out;
    int n = in_sizes[0] / 2;  // [N,2] floats

    int block = 256;
    int grid = (n + block - 1) / block;
    difftex_kernel<<<grid, block, 0, stream>>>(uvs, tex, out, n);
}

// Round 2
// 315.324 us; speedup vs baseline: 1.0461x; 1.0461x over previous
//
#include <hip/hip_runtime.h>
#include <hip/hip_fp16.h>
#include <math.h>

#define TEX_W 2048
#define TEX_H 2048

typedef float f32x4 __attribute__((ext_vector_type(4)));
typedef float f32x2 __attribute__((ext_vector_type(2)));
typedef unsigned short u16;
typedef u16 u16x8 __attribute__((ext_vector_type(8)));
typedef u16 u16x4 __attribute__((ext_vector_type(4)));

__device__ __forceinline__ float fast_tanh(float x) {
    // tanh(x) = 1 - 2/(exp(2x)+1); saturates correctly at +-inf
    float e = __expf(2.0f * x);
    return 1.0f - 2.0f * __builtin_amdgcn_rcpf(e + 1.0f);
}

__device__ __forceinline__ u16 f2h(float x) {
    return __half_as_ushort(__float2half_rn(x));
}
__device__ __forceinline__ float h2f(u16 x) {
    return __half2float(__ushort_as_half(x));
}

// Repack fp32 [H][W][3] -> fp16 half4 [H][W] (8 B/texel). 4 texels/thread.
__global__ void __launch_bounds__(256)
repack_kernel(const f32x4* __restrict__ src, u16x8* __restrict__ dst) {
    int j = blockIdx.x * blockDim.x + threadIdx.x;  // [0, 2048*2048/4)
    f32x4 A = __builtin_nontemporal_load(src + (size_t)3 * j);
    f32x4 B = __builtin_nontemporal_load(src + (size_t)3 * j + 1);
    f32x4 C = __builtin_nontemporal_load(src + (size_t)3 * j + 2);
    u16x8 lo, hi;
    lo[0] = f2h(A.x); lo[1] = f2h(A.y); lo[2] = f2h(A.z); lo[3] = 0;
    lo[4] = f2h(A.w); lo[5] = f2h(B.x); lo[6] = f2h(B.y); lo[7] = 0;
    hi[0] = f2h(B.z); hi[1] = f2h(B.w); hi[2] = f2h(C.x); hi[3] = 0;
    hi[4] = f2h(C.y); hi[5] = f2h(C.z); hi[6] = f2h(C.w); hi[7] = 0;
    dst[(size_t)2 * j]     = lo;
    dst[(size_t)2 * j + 1] = hi;
}

__device__ __forceinline__ void sample_one(float ux, float vx,
                                           const u16x4* __restrict__ texh,
                                           float* o) {
    // keep exact reference op order: ((uv + 1) * 0.5) * (W-1)
    float u = (ux + 1.0f) * 0.5f * (float)(TEX_W - 1);
    float v = (vx + 1.0f) * 0.5f * (float)(TEX_H - 1);
    float fu0 = floorf(u), fv0 = floorf(v);
    int u0 = (int)fu0, v0 = (int)fv0;
    int u1 = (int)ceilf(u), v1 = (int)ceilf(v);
    float a = u - fu0, b = v - fv0;
    float a1 = 1.0f - a, b1 = 1.0f - b;
    // reference indexes texture[u, v] -> u is the row
    u16x4 t00 = texh[u0 * TEX_W + v0];
    u16x4 t10 = texh[u1 * TEX_W + v0];
    u16x4 t01 = texh[u0 * TEX_W + v1];
    u16x4 t11 = texh[u1 * TEX_W + v1];
#pragma unroll
    for (int c = 0; c < 3; ++c) {
        float col = (h2f(t00[c]) * a + h2f(t10[c]) * a1) * b
                  + (h2f(t01[c]) * a + h2f(t11[c]) * a1) * b1;
        o[c] = fast_tanh(col);
    }
}

// 2 samples per thread
__global__ void __launch_bounds__(256)
difftex_h4(const f32x4* __restrict__ uvs2, const u16x4* __restrict__ texh,
           float* __restrict__ out, int n2) {
    int i = blockIdx.x * blockDim.x + threadIdx.x;
    if (i >= n2) return;
    f32x4 uv2 = __builtin_nontemporal_load(uvs2 + i);
    float o[6];
    sample_one(uv2.x, uv2.y, texh, o);
    sample_one(uv2.z, uv2.w, texh, o + 3);
    f32x2* ob = (f32x2*)(out + (size_t)i * 6);
    f32x2 p0 = {o[0], o[1]};
    f32x2 p1 = {o[2], o[3]};
    f32x2 p2 = {o[4], o[5]};
    __builtin_nontemporal_store(p0, ob);
    __builtin_nontemporal_store(p1, ob + 1);
    __builtin_nontemporal_store(p2, ob + 2);
}

// Fallback (round-1 kernel), used if d_ws is too small or N is odd.
__global__ void __launch_bounds__(256)
difftex_f32(const float2* __restrict__ uvs, const float* __restrict__ tex,
            float* __restrict__ out, int n) {
    int i = blockIdx.x * blockDim.x + threadIdx.x;
    if (i >= n) return;
    float2 uv = uvs[i];
    float u = (uv.x + 1.0f) * 0.5f * (float)(TEX_W - 1);
    float v = (uv.y + 1.0f) * 0.5f * (float)(TEX_H - 1);
    float fu0 = floorf(u), fv0 = floorf(v);
    int u0 = (int)fu0, v0 = (int)fv0;
    int u1 = (int)ceilf(u), v1 = (int)ceilf(v);
    float a = u - fu0, b = v - fv0;
    float a1 = 1.0f - a, b1 = 1.0f - b;
    const float* p00 = tex + ((long)u0 * TEX_W + v0) * 3;
    const float* p10 = tex + ((long)u1 * TEX_W + v0) * 3;
    const float* p01 = tex + ((long)u0 * TEX_W + v1) * 3;
    const float* p11 = tex + ((long)u1 * TEX_W + v1) * 3;
    long base = (long)i * 3;
#pragma unroll
    for (int c = 0; c < 3; ++c) {
        float col = (p00[c] * a + p10[c] * a1) * b + (p01[c] * a + p11[c] * a1) * b1;
        out[base + c] = fast_tanh(col);
    }
}

extern "C" void kernel_launch(void* const* d_in, const int* in_sizes, int n_in,
                              void* d_out, int out_size, void* d_ws, size_t ws_size,
                              hipStream_t stream) {
    const float* tex = (const float*)d_in[1];
    float* out = (float*)d_out;
    int n = in_sizes[0] / 2;  // [N,2] floats

    const size_t texh_bytes = (size_t)TEX_W * TEX_H * 8;  // 32 MiB
    if (ws_size >= texh_bytes && (n & 1) == 0) {
        // pass 1: repack texture to fp16 half4 in d_ws
        int texels4 = TEX_W * TEX_H / 4;
        repack_kernel<<<texels4 / 256, 256, 0, stream>>>(
            (const f32x4*)tex, (u16x8*)d_ws);
        // pass 2: gather + blend + tanh, 2 samples/thread
        int n2 = n / 2;
        int grid = (n2 + 255) / 256;
        difftex_h4<<<grid, 256, 0, stream>>>(
            (const f32x4*)d_in[0], (const u16x4*)d_ws, out, n2);
    } else {
        int grid = (n + 255) / 256;
        difftex_f32<<<grid, 256, 0, stream>>>(
            (const float2*)d_in[0], tex, out, n);
    }
}

// Round 4
// 206.790 us; speedup vs baseline: 1.5951x; 1.5249x over previous
//
#include <hip/hip_runtime.h>
#include <hip/hip_fp16.h>
#include <math.h>

#define TEX_W 2048
#define TEX_H 2048
#define TEX_MAX 2047

typedef float f32x4 __attribute__((ext_vector_type(4)));
typedef float f32x2 __attribute__((ext_vector_type(2)));
typedef unsigned short u16;
typedef u16 u16x4 __attribute__((ext_vector_type(4)));

__device__ __forceinline__ float fast_tanh(float x) {
    // tanh(x) = 1 - 2/(exp(2x)+1); saturates correctly at +-inf
    float e = __expf(2.0f * x);
    return 1.0f - 2.0f * __builtin_amdgcn_rcpf(e + 1.0f);
}
__device__ __forceinline__ u16 f2h(float x) {
    return __half_as_ushort(__float2half_rn(x));
}
__device__ __forceinline__ float h2f(u16 x) {
    return __half2float(__ushort_as_half(x));
}

// Quad table: one 32 B entry per texel (u,v), laid out as 4 x u16x4:
//   sub 0: t[u][v]        (c00)
//   sub 1: t[u][v+1]      (c01; col clamped at edge)
//   sub 2: t[u+1][v]      (c10; row clamped at edge)
//   sub 3: t[u+1][v+1]    (c11)
// 2048*2048*32 B = 128 MiB. Entry is 32 B aligned -> any sample reads
// exactly ONE 64 B cache line.
__global__ void __launch_bounds__(256)
build_quad(const float* __restrict__ tex, u16x4* __restrict__ q) {
    int id = blockIdx.x * blockDim.x + threadIdx.x;  // [0, 2048*2048)
    int u = id >> 11, v = id & TEX_MAX;
    int up = (u < TEX_MAX) ? u + 1 : TEX_MAX;
    int vp = (v < TEX_MAX) ? v + 1 : TEX_MAX;
    const float* t00 = tex + ((size_t)u  * TEX_W + v ) * 3;
    const float* t01 = tex + ((size_t)u  * TEX_W + vp) * 3;
    const float* t10 = tex + ((size_t)up * TEX_W + v ) * 3;
    const float* t11 = tex + ((size_t)up * TEX_W + vp) * 3;
    u16x4 e0 = {f2h(t00[0]), f2h(t00[1]), f2h(t00[2]), 0};
    u16x4 e1 = {f2h(t01[0]), f2h(t01[1]), f2h(t01[2]), 0};
    u16x4 e2 = {f2h(t10[0]), f2h(t10[1]), f2h(t10[2]), 0};
    u16x4 e3 = {f2h(t11[0]), f2h(t11[1]), f2h(t11[2]), 0};
    size_t base = (size_t)id * 4;
    q[base + 0] = e0;
    q[base + 1] = e1;
    q[base + 2] = e2;
    q[base + 3] = e3;
}

__device__ __forceinline__ void quad_one(float x, float y,
                                         const u16x4* __restrict__ q, float* o) {
    // exact reference op order: ((uv + 1) * 0.5) * (W-1)
    float u = (x + 1.0f) * 0.5f * (float)(TEX_W - 1);
    float v = (y + 1.0f) * 0.5f * (float)(TEX_H - 1);
    float fu0 = floorf(u), fv0 = floorf(v);
    int u0 = (int)fu0, v0 = (int)fv0;
    int u1 = (int)ceilf(u), v1 = (int)ceilf(v);  // exactly as reference
    float a = u - fu0, b = v - fv0;
    float a1 = 1.0f - a, b1 = 1.0f - b;
    bool ru = (u1 > u0);  // row u1 distinct from u0
    bool cv = (v1 > v0);  // col v1 distinct from v0
    size_t base = (size_t)((u0 << 11) + v0) * 4;
    u16x4 e0 = q[base + 0];
    u16x4 e1 = q[base + 1];
    u16x4 e2 = q[base + 2];
    u16x4 e3 = q[base + 3];
#pragma unroll
    for (int c = 0; c < 3; ++c) {
        float c00 = h2f(e0[c]);
        float c01 = cv ? h2f(e1[c]) : c00;               // t[u0][v1]
        float c10 = ru ? h2f(e2[c]) : c00;               // t[u1][v0]
        float c11 = ru ? (cv ? h2f(e3[c]) : c10) : c01;  // t[u1][v1]
        float col = (c00 * a + c10 * a1) * b + (c01 * a + c11 * a1) * b1;
        o[c] = fast_tanh(col);
    }
}

// 2 samples per thread
__global__ void __launch_bounds__(256)
sample_quad(const f32x4* __restrict__ uvs2, const u16x4* __restrict__ q,
            float* __restrict__ out, int n2) {
    int i = blockIdx.x * blockDim.x + threadIdx.x;
    if (i >= n2) return;
    f32x4 uv2 = __builtin_nontemporal_load(uvs2 + i);
    float o[6];
    quad_one(uv2.x, uv2.y, q, o);
    quad_one(uv2.z, uv2.w, q, o + 3);
    f32x2* ob = (f32x2*)(out + (size_t)i * 6);
    f32x2 p0 = {o[0], o[1]}, p1 = {o[2], o[3]}, p2 = {o[4], o[5]};
    __builtin_nontemporal_store(p0, ob);
    __builtin_nontemporal_store(p1, ob + 1);
    __builtin_nontemporal_store(p2, ob + 2);
}

// ---------------- fallback: fp32 direct (round-1, proven) ----------------
__global__ void __launch_bounds__(256)
difftex_f32(const float2* __restrict__ uvs, const float* __restrict__ tex,
            float* __restrict__ out, int n) {
    int i = blockIdx.x * blockDim.x + threadIdx.x;
    if (i >= n) return;
    float2 uv = uvs[i];
    float u = (uv.x + 1.0f) * 0.5f * (float)(TEX_W - 1);
    float v = (uv.y + 1.0f) * 0.5f * (float)(TEX_H - 1);
    float fu0 = floorf(u), fv0 = floorf(v);
    int u0 = (int)fu0, v0 = (int)fv0;
    int u1 = (int)ceilf(u), v1 = (int)ceilf(v);
    float a = u - fu0, b = v - fv0;
    float a1 = 1.0f - a, b1 = 1.0f - b;
    const float* p00 = tex + ((long)u0 * TEX_W + v0) * 3;
    const float* p10 = tex + ((long)u1 * TEX_W + v0) * 3;
    const float* p01 = tex + ((long)u0 * TEX_W + v1) * 3;
    const float* p11 = tex + ((long)u1 * TEX_W + v1) * 3;
    long base = (long)i * 3;
#pragma unroll
    for (int c = 0; c < 3; ++c) {
        float col = (p00[c] * a + p10[c] * a1) * b + (p01[c] * a + p11[c] * a1) * b1;
        out[base + c] = fast_tanh(col);
    }
}

extern "C" void kernel_launch(void* const* d_in, const int* in_sizes, int n_in,
                              void* d_out, int out_size, void* d_ws, size_t ws_size,
                              hipStream_t stream) {
    const float* tex = (const float*)d_in[1];
    float* out = (float*)d_out;
    int n = in_sizes[0] / 2;  // sample count

    const size_t quad_bytes = (size_t)TEX_W * TEX_H * 32;  // 128 MiB
    const int entries = TEX_W * TEX_H;

    if (ws_size >= quad_bytes && (n & 1) == 0) {
        build_quad<<<entries / 256, 256, 0, stream>>>(tex, (u16x4*)d_ws);
        int n2 = n / 2;
        sample_quad<<<(n2 + 255) / 256, 256, 0, stream>>>(
            (const f32x4*)d_in[0], (const u16x4*)d_ws, out, n2);
    } else {
        difftex_f32<<<(n + 255) / 256, 256, 0, stream>>>(
            (const float2*)d_in[0], tex, out, n);
    }
}